// Round 8
// baseline (94.324 us; speedup 1.0000x reference)
//
#include <hip/hip_runtime.h>
#include <hip/hip_bf16.h>
#include <hip/hip_fp16.h>

typedef _Float16 f16;
typedef _Float16 f16x2 __attribute__((ext_vector_type(2)));
typedef _Float16 f16x4 __attribute__((ext_vector_type(4)));
typedef _Float16 f16x8 __attribute__((ext_vector_type(8)));
typedef float f32x4 __attribute__((ext_vector_type(4)));

// Problem constants
#define NB 2
#define NS 2048
#define NDM 1024
#define NH 16
#define NK 32
#define ND 64
#define NM (NB * NS)  // 4096 rows

__device__ __forceinline__ void gload_lds16(const void* g, void* l) {
  __builtin_amdgcn_global_load_lds(
      (const __attribute__((address_space(1))) unsigned int*)g,
      (__attribute__((address_space(3))) unsigned int*)l, 16, 0, 0);
}

__device__ __forceinline__ float dot8(f16x8 a, f16x8 b, float s) {
#if __has_builtin(__builtin_amdgcn_fdot2)
#pragma unroll
  for (int e = 0; e < 4; ++e) {
    f16x2 a2 = {a[2 * e], a[2 * e + 1]};
    f16x2 b2 = {b[2 * e], b[2 * e + 1]};
    s = __builtin_amdgcn_fdot2(a2, b2, s, false);
  }
#else
#pragma unroll
  for (int e = 0; e < 8; ++e) s += (float)a[e] * (float)b[e];
#endif
  return s;
}

// ---------------- fused fp32 -> fp16 convert (x + all 4 weights) --------------
// out layout (contiguous in ws): xh[4096x1024] | Wq/8,Wk,Wv [3x1024x1024] | Wo
__global__ void cvt_all(const float* __restrict__ x, const float* __restrict__ Wq,
                        const float* __restrict__ Wk, const float* __restrict__ Wv,
                        const float* __restrict__ Wo, f16* __restrict__ out) {
  const int nx = NM * NDM / 4;    // 1048576 float4 for x
  const int nw = NDM * NDM / 4;   // 262144 float4 per weight
  int i = blockIdx.x * 256 + threadIdx.x;
  const float* src;
  float scale = 1.f;
  int r;
  if (i < nx) {
    src = x; r = i;
  } else {
    const int m = (i - nx) >> 18;  // /262144
    r = (i - nx) & (nw - 1);
    src = (m == 0) ? Wq : (m == 1) ? Wk : (m == 2) ? Wv : Wo;
    if (m == 0) scale = 0.125f;
  }
  float4 v = reinterpret_cast<const float4*>(src)[r];
  f16x4 o = {(f16)(v.x * scale), (f16)(v.y * scale), (f16)(v.z * scale), (f16)(v.w * scale)};
  reinterpret_cast<f16x4*>(out)[i] = o;
}

// ---------------- GEMM1: 256x256 tile, 8 waves, counted-vmcnt pipeline --------
// C[M,N] = A[M,K]*B[N,K]^T, fp16 in / fp32 acc, QKV-split epilogue.
// Double-buffered 128KiB LDS; stage of tile t+2 issued after the read-complete
// barrier of tile t into the freed buffer -> steady-state wait is vmcnt(8).
__global__ __launch_bounds__(512, 2) void gemm256_qkv(
    const f16* __restrict__ A, const f16* __restrict__ Bm,
    f16* __restrict__ Qo, f16* __restrict__ Kh, f16* __restrict__ Vh,
    int M, int N, int K) {
  __shared__ __align__(16) f16 As[2][256 * 64];
  __shared__ __align__(16) f16 Bs[2][256 * 64];
  const int t = threadIdx.x;          // 0..511
  const int lane = t & 63;
  const int w = t >> 6;               // 0..7
  const int wr = w >> 2, wc = w & 3;  // 2 x 4 wave grid
  const int l15 = lane & 15, l4 = lane >> 4;

  // bijective XCD swizzle over 192 blocks (24 per XCD); linear = by*12+bx
  const int bid = blockIdx.x;
  const int wg = (bid & 7) * 24 + (bid >> 3);
  const int by = wg / 12, bx = wg - by * 12;
  const long row0 = (long)by * 256;
  const long col0 = (long)bx * 256;

  const f16* Ap = A + row0 * K;
  const f16* Bp = Bm + col0 * K;

  f32x4 acc[8][4] = {};

  auto stage = [&](int kt, int buf) {
#pragma unroll
    for (int p = 0; p < 4; ++p) {
      const int s = p * 512 + t;
      const int r = s >> 3, c = s & 7;
      gload_lds16(Ap + (long)r * K + kt * 64 + ((c ^ (r & 7)) * 8), &As[buf][s * 8]);
    }
#pragma unroll
    for (int p = 0; p < 4; ++p) {
      const int s = p * 512 + t;
      const int r = s >> 3, c = s & 7;
      gload_lds16(Bp + (long)r * K + kt * 64 + ((c ^ (r & 7)) * 8), &Bs[buf][s * 8]);
    }
  };

  stage(0, 0);
  stage(1, 1);
  asm volatile("s_waitcnt vmcnt(8)" ::: "memory");  // tile 0 landed; tile 1 in flight
  __builtin_amdgcn_sched_barrier(0);
  __builtin_amdgcn_s_barrier();
  __builtin_amdgcn_sched_barrier(0);

  const int NT = K / 64;  // 16
  for (int kt = 0; kt < NT; ++kt) {
    const int cur = kt & 1;
    const f16* As_ = &As[cur][0];
    const f16* Bs_ = &Bs[cur][0];

    // B fragments (shared across quadrants): rows wc*64+nf*16+l15, chunk ks*4+l4
    f16x8 bfr[2][4];
#pragma unroll
    for (int ks = 0; ks < 2; ++ks)
#pragma unroll
      for (int nf = 0; nf < 4; ++nf) {
        const int r = wc * 64 + nf * 16 + l15;
        const int c16 = ks * 4 + l4;
        bfr[ks][nf] = *reinterpret_cast<const f16x8*>(Bs_ + r * 64 + ((c16 ^ (r & 7)) * 8));
      }
    // quadrant A-frag ping-pong
    f16x8 afA[2][2], afB[2][2];  // [mf2][ks]
#pragma unroll
    for (int mf2 = 0; mf2 < 2; ++mf2)
#pragma unroll
      for (int ks = 0; ks < 2; ++ks) {
        const int r = wr * 128 + mf2 * 16 + l15;
        const int c16 = ks * 4 + l4;
        afA[mf2][ks] = *reinterpret_cast<const f16x8*>(As_ + r * 64 + ((c16 ^ (r & 7)) * 8));
      }
#pragma unroll
    for (int q = 0; q < 4; ++q) {
      if (q < 3) {  // prefetch next quadrant into the idle reg set
#pragma unroll
        for (int mf2 = 0; mf2 < 2; ++mf2)
#pragma unroll
          for (int ks = 0; ks < 2; ++ks) {
            const int r = wr * 128 + ((q + 1) * 2 + mf2) * 16 + l15;
            const int c16 = ks * 4 + l4;
            const f16x8 v = *reinterpret_cast<const f16x8*>(As_ + r * 64 + ((c16 ^ (r & 7)) * 8));
            if (q & 1) afA[mf2][ks] = v; else afB[mf2][ks] = v;
          }
      }
      __builtin_amdgcn_s_setprio(1);
#pragma unroll
      for (int mf2 = 0; mf2 < 2; ++mf2)
#pragma unroll
        for (int ks = 0; ks < 2; ++ks)
#pragma unroll
          for (int nf = 0; nf < 4; ++nf) {
            const f16x8 a = (q & 1) ? afB[mf2][ks] : afA[mf2][ks];
            acc[q * 2 + mf2][nf] = __builtin_amdgcn_mfma_f32_16x16x32_f16(
                a, bfr[ks][nf], acc[q * 2 + mf2][nf], 0, 0, 0);
          }
      __builtin_amdgcn_s_setprio(0);
    }
    // all this wave's LDS reads done before anyone overwrites buf cur
    asm volatile("s_waitcnt lgkmcnt(0)" ::: "memory");
    __builtin_amdgcn_sched_barrier(0);
    __builtin_amdgcn_s_barrier();
    __builtin_amdgcn_sched_barrier(0);
    if (kt + 2 < NT) {
      stage(kt + 2, cur);  // into the buffer just freed
      asm volatile("s_waitcnt vmcnt(8)" ::: "memory");  // tile kt+1 complete
    } else if (kt + 1 < NT) {
      asm volatile("s_waitcnt vmcnt(0)" ::: "memory");  // last prefetch drain
    }
    if (kt + 1 < NT) {
      __builtin_amdgcn_sched_barrier(0);
      __builtin_amdgcn_s_barrier();  // buf kt+1 collectively staged
      __builtin_amdgcn_sched_barrier(0);
    }
  }

  // ---- epilogue: QKV split ----
#pragma unroll
  for (int mf = 0; mf < 8; ++mf)
#pragma unroll
    for (int nf = 0; nf < 4; ++nf) {
      const long col = col0 + wc * 64 + nf * 16 + l15;
#pragma unroll
      for (int r = 0; r < 4; ++r) {
        const long row = row0 + wr * 128 + mf * 16 + l4 * 4 + r;
        const float val = acc[mf][nf][r];
        if (col < 1024) {
          Qo[row * 1024 + col] = (f16)val;
        } else {
          const long n2 = col - 1024;
          const int mat = (int)(n2 >> 10);  // 0=K, 1=V
          const int hh = (int)((n2 & 1023) >> 6);
          const int dd = (int)(n2 & 63);
          const int bb = (int)(row >> 11), ss = (int)(row & 2047);
          f16* dst = mat ? Vh : Kh;
          dst[(((long)bb * 16 + hh) * 2048 + ss) * 64 + dd] = (f16)val;
        }
      }
    }
}

// ---------------- GEMM2 (128x128, m97-style) ----------------------------------
__global__ __launch_bounds__(256, 2) void gemm_bt_f32(
    const f16* __restrict__ A, const f16* __restrict__ Bm,
    float* __restrict__ Cf32, int M, int N, int K) {
  __shared__ __align__(16) f16 As[128 * 64];
  __shared__ __align__(16) f16 Bs[128 * 64];
  const int t = threadIdx.x;
  const int lane = t & 63;
  const int w = t >> 6;
  const int wr = w >> 1, wc = w & 1;
  const long row0 = (long)blockIdx.y * 128;
  const long col0 = (long)blockIdx.x * 128;

  const f16* Ap = A + row0 * K;
  const f16* Bp = Bm + col0 * K;

  f32x4 acc[4][4] = {};

  for (int kt = 0; kt < K; kt += 64) {
#pragma unroll
    for (int i = 0; i < 4; ++i) {
      const int s = i * 256 + t;
      const int r = s >> 3, c = s & 7;
      const int cs = c ^ (r & 7);
      gload_lds16(Ap + (long)r * K + kt + cs * 8, As + s * 8);
      gload_lds16(Bp + (long)r * K + kt + cs * 8, Bs + s * 8);
    }
    __syncthreads();
#pragma unroll
    for (int ks = 0; ks < 2; ++ks) {
      const int kch = ks * 4 + (lane >> 4);
      f16x8 af[4], bf[4];
#pragma unroll
      for (int mf = 0; mf < 4; ++mf) {
        const int rr = wr * 64 + mf * 16 + (lane & 15);
        af[mf] = *reinterpret_cast<const f16x8*>(As + rr * 64 + ((kch ^ (rr & 7)) * 8));
      }
#pragma unroll
      for (int nf = 0; nf < 4; ++nf) {
        const int rr = wc * 64 + nf * 16 + (lane & 15);
        bf[nf] = *reinterpret_cast<const f16x8*>(Bs + rr * 64 + ((kch ^ (rr & 7)) * 8));
      }
#pragma unroll
      for (int mf = 0; mf < 4; ++mf)
#pragma unroll
        for (int nf = 0; nf < 4; ++nf)
          acc[mf][nf] = __builtin_amdgcn_mfma_f32_16x16x32_f16(af[mf], bf[nf], acc[mf][nf], 0, 0, 0);
    }
    __syncthreads();
  }

#pragma unroll
  for (int mf = 0; mf < 4; ++mf)
#pragma unroll
    for (int nf = 0; nf < 4; ++nf) {
      const long col = col0 + wc * 64 + nf * 16 + (lane & 15);
#pragma unroll
      for (int r = 0; r < 4; ++r) {
        const long row = row0 + wr * 64 + mf * 16 + (lane >> 4) * 4 + r;
        Cf32[row * N + col] = acc[mf][nf][r];
      }
    }
}

// ---------------- sparse attention v7: lane-local softmax/PV ------------------
__global__ __launch_bounds__(256) void attn_v7(
    const f16* __restrict__ qm,        // [4096][1024]  (pre-scaled q)
    const f16* __restrict__ Kh,        // [(b*16+h)*2048 + s][64]
    const f16* __restrict__ Vh,        // same layout
    const int* __restrict__ attn_idx,  // [4096][32]
    f16* __restrict__ aout) {          // [4096][1024]
  __shared__ f16 qs[32][72];
  __shared__ int ism[32][36];

  const int t = threadIdx.x;
  const int w = t >> 6, lane = t & 63;

  const int bid = blockIdx.x;
  const int combo = 4 * (bid & 7) + ((bid >> 3) & 3);
  const int chunk = bid >> 5;
  const int b = combo >> 4, h = combo & 15;
  const int s0 = chunk * 32;
  const long kvbase = (long)combo * 2048 * 64;

  {
    const int bq = t >> 3, part = t & 7;
    const long row = (long)(b * 2048 + s0 + bq);
    *reinterpret_cast<f16x8*>(&qs[bq][part * 8]) =
        *reinterpret_cast<const f16x8*>(qm + row * 1024 + h * 64 + part * 8);
    const int4 iv = *reinterpret_cast<const int4*>(attn_idx + row * 32 + part * 4);
    *reinterpret_cast<int4*>(&ism[bq][part * 4]) = iv;
  }
  __syncthreads();

  const int qg = lane >> 3, c = lane & 7;
  const int bq = w * 8 + qg;
  const f16x8 qv = *reinterpret_cast<const f16x8*>(&qs[bq][c * 8]);
  const f16* kbase = Kh + kvbase + c * 8;
  const f16* vbase = Vh + kvbase + c * 8;

  float sc[32];
#pragma unroll
  for (int jb = 0; jb < 8; ++jb) {
    const int4 r4 = *reinterpret_cast<const int4*>(&ism[bq][jb * 4]);
    const int rr[4] = {r4.x, r4.y, r4.z, r4.w};
#pragma unroll
    for (int i = 0; i < 4; ++i) {
      const f16x8 kk = *reinterpret_cast<const f16x8*>(kbase + (long)rr[i] * 64);
      float s = dot8(qv, kk, 0.f);
      s += __shfl_xor(s, 1, 64);
      s += __shfl_xor(s, 2, 64);
      s += __shfl_xor(s, 4, 64);
      sc[jb * 4 + i] = s;
    }
  }

  float m = sc[0];
#pragma unroll
  for (int jj = 1; jj < 32; ++jj) m = fmaxf(m, sc[jj]);
  float sum = 0.f;
#pragma unroll
  for (int jj = 0; jj < 32; ++jj) {
    sc[jj] = __expf(sc[jj] - m);
    sum += sc[jj];
  }
  const float inv = __frcp_rn(sum);

  float acc[8] = {};
#pragma unroll
  for (int jb = 0; jb < 8; ++jb) {
    const int4 r4 = *reinterpret_cast<const int4*>(&ism[bq][jb * 4]);
    const int rr[4] = {r4.x, r4.y, r4.z, r4.w};
#pragma unroll
    for (int i = 0; i < 4; ++i) {
      const f16x8 vv = *reinterpret_cast<const f16x8*>(vbase + (long)rr[i] * 64);
      const float p = sc[jb * 4 + i];
#pragma unroll
      for (int e = 0; e < 8; ++e) acc[e] += p * (float)vv[e];
    }
  }
  f16x8 oo;
#pragma unroll
  for (int e = 0; e < 8; ++e) oo[e] = (f16)(acc[e] * inv);
  const long orow = (long)(b * 2048 + s0 + bq);
  *reinterpret_cast<f16x8*>(aout + orow * 1024 + h * 64 + c * 8) = oo;
}

// ---------------- launch ------------------------------------------------------
extern "C" void kernel_launch(void* const* d_in, const int* in_sizes, int n_in,
                              void* d_out, int out_size, void* d_ws, size_t ws_size,
                              hipStream_t stream) {
  const float* x = (const float*)d_in[0];
  const int* aidx = (const int*)d_in[1];
  // d_in[2] = attn_mask: all-true in this problem, ignored
  const float* Wq = (const float*)d_in[3];
  const float* Wk = (const float*)d_in[4];
  const float* Wv = (const float*)d_in[5];
  const float* Wo = (const float*)d_in[6];
  float* out = (float*)d_out;

  f16* xh = (f16*)d_ws;                      // 4096x1024
  f16* wqkv = xh + (long)NM * NDM;           // 3072x1024 (Wq/8, Wk, Wv stacked)
  f16* woh = wqkv + (long)3 * NDM * NDM;     // 1024x1024
  f16* qm = woh + (long)NDM * NDM;           // 4096x1024 (q, scaled)
  f16* Khm = qm + (long)NM * NDM;            // 2*16*2048*64
  f16* Vhm = Khm + (long)NM * NDM;           // 2*16*2048*64
  f16* aout = Vhm + (long)NM * NDM;          // 4096x1024

  cvt_all<<<(NM * NDM / 4 + 4 * NDM * NDM / 4) / 256, 256, 0, stream>>>(
      x, Wq, Wk, Wv, Wo, xh);

  gemm256_qkv<<<192, 512, 0, stream>>>(xh, wqkv, qm, Khm, Vhm, NM, 3 * NDM, NDM);

  attn_v7<<<2048, 256, 0, stream>>>(qm, Khm, Vhm, aidx, aout);

  dim3 g2(NDM / 128, NM / 128);  // 8 x 32
  gemm_bt_f32<<<g2, 256, 0, stream>>>(aout, woh, out, NM, NDM, NDM);
}

// Round 9
// 91.588 us; speedup vs baseline: 1.0299x; 1.0299x over previous
//
#include <hip/hip_runtime.h>
#include <hip/hip_bf16.h>
#include <hip/hip_fp16.h>

typedef _Float16 f16;
typedef _Float16 f16x2 __attribute__((ext_vector_type(2)));
typedef _Float16 f16x4 __attribute__((ext_vector_type(4)));
typedef _Float16 f16x8 __attribute__((ext_vector_type(8)));
typedef float f32x4 __attribute__((ext_vector_type(4)));

// Problem constants
#define NB 2
#define NS 2048
#define NDM 1024
#define NH 16
#define NK 32
#define ND 64
#define NM (NB * NS)  // 4096 rows

__device__ __forceinline__ void gload_lds16(const void* g, void* l) {
  __builtin_amdgcn_global_load_lds(
      (const __attribute__((address_space(1))) unsigned int*)g,
      (__attribute__((address_space(3))) unsigned int*)l, 16, 0, 0);
}

__device__ __forceinline__ float dot8(f16x8 a, f16x8 b, float s) {
#if __has_builtin(__builtin_amdgcn_fdot2)
#pragma unroll
  for (int e = 0; e < 4; ++e) {
    f16x2 a2 = {a[2 * e], a[2 * e + 1]};
    f16x2 b2 = {b[2 * e], b[2 * e + 1]};
    s = __builtin_amdgcn_fdot2(a2, b2, s, false);
  }
#else
#pragma unroll
  for (int e = 0; e < 8; ++e) s += (float)a[e] * (float)b[e];
#endif
  return s;
}

// ---------------- fused fp32 -> fp16 convert (x + all 4 weights) --------------
__global__ void cvt_all(const float* __restrict__ x, const float* __restrict__ Wq,
                        const float* __restrict__ Wk, const float* __restrict__ Wv,
                        const float* __restrict__ Wo, f16* __restrict__ out) {
  const int nx = NM * NDM / 4;    // float4 count for x
  const int nw = NDM * NDM / 4;   // per weight
  int i = blockIdx.x * 256 + threadIdx.x;
  const float* src;
  float scale = 1.f;
  int r;
  if (i < nx) {
    src = x; r = i;
  } else {
    const int m = (i - nx) >> 18;
    r = (i - nx) & (nw - 1);
    src = (m == 0) ? Wq : (m == 1) ? Wk : (m == 2) ? Wv : Wo;
    if (m == 0) scale = 0.125f;
  }
  float4 v = reinterpret_cast<const float4*>(src)[r];
  f16x4 o = {(f16)(v.x * scale), (f16)(v.y * scale), (f16)(v.z * scale), (f16)(v.w * scale)};
  reinterpret_cast<f16x4*>(out)[i] = o;
}

// ---------------- GEMM1: 256x256, 8-wave, true 8-phase counted-vmcnt ----------
// Tiles: even K-tile -> buf0, odd -> buf1. Per iteration (E=2i, O=E+1):
//   p0: E q0 (+B frags), stage O.A0+A1    p4: O q0 (+B frags), stage (E+2).A0
//   p1: E q1, stage (E+2).B0              p5: O q1, stage (E+2).A1
//   p2: E q2, stage (E+2).B1              p6: O q2, stage (O+2).B0
//   p3: E q3, vmcnt(4) at end            p7: O q3, stage (O+2).B1, vmcnt(4)
// Ledger-checked: every tile's halves land before first ds_read; steady-state
// leaves 2 half-tiles (4 loads) in flight across each counted wait.
#define PH_DS_B(TSB)                                                          \
  _Pragma("unroll") for (int ks = 0; ks < 2; ++ks)                            \
  _Pragma("unroll") for (int nf = 0; nf < 4; ++nf) {                          \
    const int r = wc * 64 + nf * 16 + l15;                                    \
    const int c16 = ks * 4 + l4;                                              \
    bfr[ks][nf] = *reinterpret_cast<const f16x8*>(                            \
        (TSB) + r * 64 + ((c16 ^ (r & 7)) * 8));                              \
  }

#define PHASE(TSA, TSB, Q, LOADB, STAGE_STMT, VM_STMT)                        \
  {                                                                           \
    if (LOADB) { PH_DS_B(TSB) }                                               \
    f16x8 af[2][2];                                                           \
    _Pragma("unroll") for (int mf2 = 0; mf2 < 2; ++mf2)                       \
    _Pragma("unroll") for (int ks = 0; ks < 2; ++ks) {                        \
      const int r = wr * 128 + ((Q)*2 + mf2) * 16 + l15;                      \
      const int c16 = ks * 4 + l4;                                            \
      af[mf2][ks] = *reinterpret_cast<const f16x8*>(                          \
          (TSA) + r * 64 + ((c16 ^ (r & 7)) * 8));                            \
    }                                                                         \
    STAGE_STMT;                                                               \
    __builtin_amdgcn_s_barrier();                                             \
    asm volatile("s_waitcnt lgkmcnt(0)" ::: "memory");                        \
    __builtin_amdgcn_sched_barrier(0);                                        \
    __builtin_amdgcn_s_setprio(1);                                            \
    _Pragma("unroll") for (int mf2 = 0; mf2 < 2; ++mf2)                       \
    _Pragma("unroll") for (int ks = 0; ks < 2; ++ks)                          \
    _Pragma("unroll") for (int nf = 0; nf < 4; ++nf)                          \
      acc[(Q)*2 + mf2][nf] = __builtin_amdgcn_mfma_f32_16x16x32_f16(          \
          af[mf2][ks], bfr[ks][nf], acc[(Q)*2 + mf2][nf], 0, 0, 0);           \
    __builtin_amdgcn_s_setprio(0);                                            \
    VM_STMT;                                                                  \
    __builtin_amdgcn_s_barrier();                                             \
  }

#define VMW(N)                                                                \
  asm volatile("s_waitcnt vmcnt(" #N ")" ::: "memory");                       \
  __builtin_amdgcn_sched_barrier(0)

__global__ __launch_bounds__(512, 1) void gemm256_8ph(
    const f16* __restrict__ A, const f16* __restrict__ Bm,
    f16* __restrict__ Qo, f16* __restrict__ Kh, f16* __restrict__ Vh,
    int M, int N, int K) {
  __shared__ __align__(16) f16 As[2][256 * 64];
  __shared__ __align__(16) f16 Bs[2][256 * 64];
  const int t = threadIdx.x;
  const int lane = t & 63;
  const int w = t >> 6;
  const int wr = w >> 2, wc = w & 3;  // 2 x 4 wave grid
  const int l15 = lane & 15, l4 = lane >> 4;

  // bijective XCD swizzle over 192 blocks (24/XCD)
  const int bid = blockIdx.x;
  const int wg = (bid & 7) * 24 + (bid >> 3);
  const int by = wg / 12, bx = wg - by * 12;
  const long row0 = (long)by * 256;
  const long col0 = (long)bx * 256;

  const f16* Ap = A + row0 * K;
  const f16* Bp = Bm + col0 * K;

  f32x4 acc[8][4] = {};
  f16x8 bfr[2][4];

  // stage one half-tile (128 rows x 64 cols) of tile u: 2 gload_lds / thread
  auto stgA = [&](int u, int hf) {
#pragma unroll
    for (int p = 0; p < 2; ++p) {
      const int s = p * 512 + t;
      const int rl = s >> 3, c = s & 7;
      gload_lds16(Ap + (long)(hf * 128 + rl) * K + u * 64 + ((c ^ (rl & 7)) * 8),
                  &As[u & 1][hf * 8192 + s * 8]);
    }
  };
  auto stgB = [&](int u, int hf) {
#pragma unroll
    for (int p = 0; p < 2; ++p) {
      const int s = p * 512 + t;
      const int rl = s >> 3, c = s & 7;
      gload_lds16(Bp + (long)(hf * 128 + rl) * K + u * 64 + ((c ^ (rl & 7)) * 8),
                  &Bs[u & 1][hf * 8192 + s * 8]);
    }
  };

  // prologue: t0 fully + t1.B; wait t0 landed (t1.B stays in flight)
  stgA(0, 0); stgA(0, 1); stgB(0, 0); stgB(0, 1);
  stgB(1, 0); stgB(1, 1);
  VMW(4);
  __builtin_amdgcn_s_barrier();

  const int NT = K / 64;  // 16
  const f16* A0 = &As[0][0];
  const f16* B0 = &Bs[0][0];
  const f16* A1 = &As[1][0];
  const f16* B1 = &Bs[1][0];

  for (int it2 = 0; it2 < NT / 2; ++it2) {
    const int E = it2 * 2, O = E + 1;
    const bool nE = (E + 2) < NT;  // also covers O+2<NT (same parity window)
    // ---- tile E (buf0) ----
    PHASE(A0, B0, 0, true,  { stgA(O, 0); stgA(O, 1); }, {});
    PHASE(A0, B0, 1, false, { if (nE) stgB(E + 2, 0); }, {});
    PHASE(A0, B0, 2, false, { if (nE) stgB(E + 2, 1); }, {});
    PHASE(A0, B0, 3, false, {}, { if (nE) { VMW(4); } else { VMW(0); } });
    // ---- tile O (buf1) ----
    PHASE(A1, B1, 0, true,  { if (nE) stgA(E + 2, 0); }, {});
    PHASE(A1, B1, 1, false, { if (nE) stgA(E + 2, 1); }, {});
    PHASE(A1, B1, 2, false, { if (nE) stgB(O + 2, 0); }, {});
    PHASE(A1, B1, 3, false, { if (nE) stgB(O + 2, 1); }, { if (nE) { VMW(4); } });
  }

  // ---- epilogue: QKV split ----
#pragma unroll
  for (int mf = 0; mf < 8; ++mf)
#pragma unroll
    for (int nf = 0; nf < 4; ++nf) {
      const long col = col0 + wc * 64 + nf * 16 + l15;
#pragma unroll
      for (int r = 0; r < 4; ++r) {
        const long row = row0 + wr * 128 + mf * 16 + l4 * 4 + r;
        const float val = acc[mf][nf][r];
        if (col < 1024) {
          Qo[row * 1024 + col] = (f16)val;
        } else {
          const long n2 = col - 1024;
          const int mat = (int)(n2 >> 10);  // 0=K, 1=V
          const int hh = (int)((n2 & 1023) >> 6);
          const int dd = (int)(n2 & 63);
          const int bb = (int)(row >> 11), ss = (int)(row & 2047);
          f16* dst = mat ? Vh : Kh;
          dst[(((long)bb * 16 + hh) * 2048 + ss) * 64 + dd] = (f16)val;
        }
      }
    }
}

// ---------------- GEMM2 (128x128, m97-style) ----------------------------------
__global__ __launch_bounds__(256, 2) void gemm_bt_f32(
    const f16* __restrict__ A, const f16* __restrict__ Bm,
    float* __restrict__ Cf32, int M, int N, int K) {
  __shared__ __align__(16) f16 As[128 * 64];
  __shared__ __align__(16) f16 Bs[128 * 64];
  const int t = threadIdx.x;
  const int lane = t & 63;
  const int w = t >> 6;
  const int wr = w >> 1, wc = w & 1;
  const long row0 = (long)blockIdx.y * 128;
  const long col0 = (long)blockIdx.x * 128;

  const f16* Ap = A + row0 * K;
  const f16* Bp = Bm + col0 * K;

  f32x4 acc[4][4] = {};

  for (int kt = 0; kt < K; kt += 64) {
#pragma unroll
    for (int i = 0; i < 4; ++i) {
      const int s = i * 256 + t;
      const int r = s >> 3, c = s & 7;
      const int cs = c ^ (r & 7);
      gload_lds16(Ap + (long)r * K + kt + cs * 8, As + s * 8);
      gload_lds16(Bp + (long)r * K + kt + cs * 8, Bs + s * 8);
    }
    __syncthreads();
#pragma unroll
    for (int ks = 0; ks < 2; ++ks) {
      const int kch = ks * 4 + (lane >> 4);
      f16x8 af[4], bf[4];
#pragma unroll
      for (int mf = 0; mf < 4; ++mf) {
        const int rr = wr * 64 + mf * 16 + (lane & 15);
        af[mf] = *reinterpret_cast<const f16x8*>(As + rr * 64 + ((kch ^ (rr & 7)) * 8));
      }
#pragma unroll
      for (int nf = 0; nf < 4; ++nf) {
        const int rr = wc * 64 + nf * 16 + (lane & 15);
        bf[nf] = *reinterpret_cast<const f16x8*>(Bs + rr * 64 + ((kch ^ (rr & 7)) * 8));
      }
#pragma unroll
      for (int mf = 0; mf < 4; ++mf)
#pragma unroll
        for (int nf = 0; nf < 4; ++nf)
          acc[mf][nf] = __builtin_amdgcn_mfma_f32_16x16x32_f16(af[mf], bf[nf], acc[mf][nf], 0, 0, 0);
    }
    __syncthreads();
  }

#pragma unroll
  for (int mf = 0; mf < 4; ++mf)
#pragma unroll
    for (int nf = 0; nf < 4; ++nf) {
      const long col = col0 + wc * 64 + nf * 16 + (lane & 15);
#pragma unroll
      for (int r = 0; r < 4; ++r) {
        const long row = row0 + wr * 64 + mf * 16 + (lane >> 4) * 4 + r;
        Cf32[row * N + col] = acc[mf][nf][r];
      }
    }
}

// ---------------- sparse attention v7: lane-local softmax/PV ------------------
__global__ __launch_bounds__(256) void attn_v7(
    const f16* __restrict__ qm, const f16* __restrict__ Kh,
    const f16* __restrict__ Vh, const int* __restrict__ attn_idx,
    f16* __restrict__ aout) {
  __shared__ f16 qs[32][72];
  __shared__ int ism[32][36];

  const int t = threadIdx.x;
  const int w = t >> 6, lane = t & 63;

  const int bid = blockIdx.x;
  const int combo = 4 * (bid & 7) + ((bid >> 3) & 3);
  const int chunk = bid >> 5;
  const int b = combo >> 4, h = combo & 15;
  const int s0 = chunk * 32;
  const long kvbase = (long)combo * 2048 * 64;

  {
    const int bq = t >> 3, part = t & 7;
    const long row = (long)(b * 2048 + s0 + bq);
    *reinterpret_cast<f16x8*>(&qs[bq][part * 8]) =
        *reinterpret_cast<const f16x8*>(qm + row * 1024 + h * 64 + part * 8);
    const int4 iv = *reinterpret_cast<const int4*>(attn_idx + row * 32 + part * 4);
    *reinterpret_cast<int4*>(&ism[bq][part * 4]) = iv;
  }
  __syncthreads();

  const int qg = lane >> 3, c = lane & 7;
  const int bq = w * 8 + qg;
  const f16x8 qv = *reinterpret_cast<const f16x8*>(&qs[bq][c * 8]);
  const f16* kbase = Kh + kvbase + c * 8;
  const f16* vbase = Vh + kvbase + c * 8;

  float sc[32];
#pragma unroll
  for (int jb = 0; jb < 8; ++jb) {
    const int4 r4 = *reinterpret_cast<const int4*>(&ism[bq][jb * 4]);
    const int rr[4] = {r4.x, r4.y, r4.z, r4.w};
#pragma unroll
    for (int i = 0; i < 4; ++i) {
      const f16x8 kk = *reinterpret_cast<const f16x8*>(kbase + (long)rr[i] * 64);
      float s = dot8(qv, kk, 0.f);
      s += __shfl_xor(s, 1, 64);
      s += __shfl_xor(s, 2, 64);
      s += __shfl_xor(s, 4, 64);
      sc[jb * 4 + i] = s;
    }
  }

  float m = sc[0];
#pragma unroll
  for (int jj = 1; jj < 32; ++jj) m = fmaxf(m, sc[jj]);
  float sum = 0.f;
#pragma unroll
  for (int jj = 0; jj < 32; ++jj) {
    sc[jj] = __expf(sc[jj] - m);
    sum += sc[jj];
  }
  const float inv = __frcp_rn(sum);

  float acc[8] = {};
#pragma unroll
  for (int jb = 0; jb < 8; ++jb) {
    const int4 r4 = *reinterpret_cast<const int4*>(&ism[bq][jb * 4]);
    const int rr[4] = {r4.x, r4.y, r4.z, r4.w};
#pragma unroll
    for (int i = 0; i < 4; ++i) {
      const f16x8 vv = *reinterpret_cast<const f16x8*>(vbase + (long)rr[i] * 64);
      const float p = sc[jb * 4 + i];
#pragma unroll
      for (int e = 0; e < 8; ++e) acc[e] += p * (float)vv[e];
    }
  }
  f16x8 oo;
#pragma unroll
  for (int e = 0; e < 8; ++e) oo[e] = (f16)(acc[e] * inv);
  const long orow = (long)(b * 2048 + s0 + bq);
  *reinterpret_cast<f16x8*>(aout + orow * 1024 + h * 64 + c * 8) = oo;
}

// ---------------- launch ------------------------------------------------------
extern "C" void kernel_launch(void* const* d_in, const int* in_sizes, int n_in,
                              void* d_out, int out_size, void* d_ws, size_t ws_size,
                              hipStream_t stream) {
  const float* x = (const float*)d_in[0];
  const int* aidx = (const int*)d_in[1];
  const float* Wq = (const float*)d_in[3];
  const float* Wk = (const float*)d_in[4];
  const float* Wv = (const float*)d_in[5];
  const float* Wo = (const float*)d_in[6];
  float* out = (float*)d_out;

  f16* xh = (f16*)d_ws;                      // 4096x1024
  f16* wqkv = xh + (long)NM * NDM;           // 3072x1024
  f16* woh = wqkv + (long)3 * NDM * NDM;     // 1024x1024
  f16* qm = woh + (long)NDM * NDM;           // 4096x1024 (q, scaled)
  f16* Khm = qm + (long)NM * NDM;
  f16* Vhm = Khm + (long)NM * NDM;
  f16* aout = Vhm + (long)NM * NDM;

  cvt_all<<<(NM * NDM / 4 + 4 * NDM * NDM / 4) / 256, 256, 0, stream>>>(
      x, Wq, Wk, Wv, Wo, xh);

  gemm256_8ph<<<192, 512, 0, stream>>>(xh, wqkv, qm, Khm, Vhm, NM, 3 * NDM, NDM);

  attn_v7<<<2048, 256, 0, stream>>>(qm, Khm, Vhm, aidx, aout);

  dim3 g2(NDM / 128, NM / 128);  // 8 x 32
  gemm_bt_f32<<<g2, 256, 0, stream>>>(aout, woh, out, NM, NDM, NDM);
}

// Round 10
// 85.019 us; speedup vs baseline: 1.1094x; 1.0773x over previous
//
#include <hip/hip_runtime.h>
#include <hip/hip_bf16.h>
#include <hip/hip_fp16.h>

typedef _Float16 f16;
typedef _Float16 f16x2 __attribute__((ext_vector_type(2)));
typedef _Float16 f16x4 __attribute__((ext_vector_type(4)));
typedef _Float16 f16x8 __attribute__((ext_vector_type(8)));
typedef float f32x4 __attribute__((ext_vector_type(4)));

// Problem constants
#define NB 2
#define NS 2048
#define NDM 1024
#define NH 16
#define NK 32
#define ND 64
#define NM (NB * NS)  // 4096 rows

__device__ __forceinline__ void gload_lds16(const void* g, void* l) {
  __builtin_amdgcn_global_load_lds(
      (const __attribute__((address_space(1))) unsigned int*)g,
      (__attribute__((address_space(3))) unsigned int*)l, 16, 0, 0);
}

__device__ __forceinline__ float dot8(f16x8 a, f16x8 b, float s) {
#if __has_builtin(__builtin_amdgcn_fdot2)
#pragma unroll
  for (int e = 0; e < 4; ++e) {
    f16x2 a2 = {a[2 * e], a[2 * e + 1]};
    f16x2 b2 = {b[2 * e], b[2 * e + 1]};
    s = __builtin_amdgcn_fdot2(a2, b2, s, false);
  }
#else
#pragma unroll
  for (int e = 0; e < 8; ++e) s += (float)a[e] * (float)b[e];
#endif
  return s;
}

// ---------------- fused fp32 -> fp16 convert (x + all 4 weights) --------------
__global__ void cvt_all(const float* __restrict__ x, const float* __restrict__ Wq,
                        const float* __restrict__ Wk, const float* __restrict__ Wv,
                        const float* __restrict__ Wo, f16* __restrict__ out) {
  const int nx = NM * NDM / 4;
  const int nw = NDM * NDM / 4;
  int i = blockIdx.x * 256 + threadIdx.x;
  const float* src;
  float scale = 1.f;
  int r;
  if (i < nx) {
    src = x; r = i;
  } else {
    const int m = (i - nx) >> 18;
    r = (i - nx) & (nw - 1);
    src = (m == 0) ? Wq : (m == 1) ? Wk : (m == 2) ? Wv : Wo;
    if (m == 0) scale = 0.125f;
  }
  float4 v = reinterpret_cast<const float4*>(src)[r];
  f16x4 o = {(f16)(v.x * scale), (f16)(v.y * scale), (f16)(v.z * scale), (f16)(v.w * scale)};
  reinterpret_cast<f16x4*>(out)[i] = o;
}

// ---------------- GEMM1: 128x128 m97-structure, QKV-split epilogue ------------
// C[M,N] = A[M,K]*B[N,K]^T, fp16 in / fp32 acc.
// col<1024 -> q[M][1024]; 1024..2048 -> Kh head-major; 2048..3072 -> Vh.
__global__ __launch_bounds__(256, 2) void gemm128_qkv(
    const f16* __restrict__ A, const f16* __restrict__ Bm,
    f16* __restrict__ Qo, f16* __restrict__ Kh, f16* __restrict__ Vh,
    int M, int N, int K) {
  __shared__ __align__(16) f16 As[128 * 64];
  __shared__ __align__(16) f16 Bs[128 * 64];
  const int t = threadIdx.x;
  const int lane = t & 63;
  const int w = t >> 6;
  const int wr = w >> 1, wc = w & 1;
  const long row0 = (long)blockIdx.y * 128;
  const long col0 = (long)blockIdx.x * 128;

  const f16* Ap = A + row0 * K;
  const f16* Bp = Bm + col0 * K;

  f32x4 acc[4][4] = {};

  for (int kt = 0; kt < K; kt += 64) {
#pragma unroll
    for (int i = 0; i < 4; ++i) {
      const int s = i * 256 + t;       // 128 rows x 8 chunks
      const int r = s >> 3, c = s & 7;
      const int cs = c ^ (r & 7);      // pre-swizzled source
      gload_lds16(Ap + (long)r * K + kt + cs * 8, As + s * 8);
      gload_lds16(Bp + (long)r * K + kt + cs * 8, Bs + s * 8);
    }
    __syncthreads();
#pragma unroll
    for (int ks = 0; ks < 2; ++ks) {
      const int kch = ks * 4 + (lane >> 4);
      f16x8 af[4], bf[4];
#pragma unroll
      for (int mf = 0; mf < 4; ++mf) {
        const int rr = wr * 64 + mf * 16 + (lane & 15);
        af[mf] = *reinterpret_cast<const f16x8*>(As + rr * 64 + ((kch ^ (rr & 7)) * 8));
      }
#pragma unroll
      for (int nf = 0; nf < 4; ++nf) {
        const int rr = wc * 64 + nf * 16 + (lane & 15);
        bf[nf] = *reinterpret_cast<const f16x8*>(Bs + rr * 64 + ((kch ^ (rr & 7)) * 8));
      }
#pragma unroll
      for (int mf = 0; mf < 4; ++mf)
#pragma unroll
        for (int nf = 0; nf < 4; ++nf)
          acc[mf][nf] = __builtin_amdgcn_mfma_f32_16x16x32_f16(af[mf], bf[nf], acc[mf][nf], 0, 0, 0);
    }
    __syncthreads();
  }

#pragma unroll
  for (int mf = 0; mf < 4; ++mf)
#pragma unroll
    for (int nf = 0; nf < 4; ++nf) {
      const long col = col0 + wc * 64 + nf * 16 + (lane & 15);
#pragma unroll
      for (int r = 0; r < 4; ++r) {
        const long row = row0 + wr * 64 + mf * 16 + (lane >> 4) * 4 + r;
        const float val = acc[mf][nf][r];
        if (col < 1024) {
          Qo[row * 1024 + col] = (f16)val;
        } else {
          const long n2 = col - 1024;
          const int mat = (int)(n2 >> 10);  // 0=K, 1=V
          const int hh = (int)((n2 & 1023) >> 6);
          const int dd = (int)(n2 & 63);
          const int bb = (int)(row >> 11), ss = (int)(row & 2047);
          f16* dst = mat ? Vh : Kh;
          dst[(((long)bb * 16 + hh) * 2048 + ss) * 64 + dd] = (f16)val;
        }
      }
    }
}

// ---------------- GEMM2: 128x64 tile -> 512 blocks = 2 blocks/CU --------------
// C[M,N] = A[M,K]*B[N,K]^T, f32 out. 4 waves in 2x2; wave tile 64x32.
__global__ __launch_bounds__(256, 2) void gemm128x64_f32(
    const f16* __restrict__ A, const f16* __restrict__ Bm,
    float* __restrict__ Cf32, int M, int N, int K) {
  __shared__ __align__(16) f16 As[128 * 64];  // 16 KB
  __shared__ __align__(16) f16 Bs[64 * 64];   //  8 KB
  const int t = threadIdx.x;
  const int lane = t & 63;
  const int w = t >> 6;
  const int wr = w >> 1, wc = w & 1;  // 2(M) x 2(N)
  const int l15 = lane & 15, l4 = lane >> 4;
  const long row0 = (long)blockIdx.y * 128;
  const long col0 = (long)blockIdx.x * 64;

  const f16* Ap = A + row0 * K;
  const f16* Bp = Bm + col0 * K;

  f32x4 acc[4][2] = {};

  for (int kt = 0; kt < K; kt += 64) {
#pragma unroll
    for (int i = 0; i < 4; ++i) {
      const int s = i * 256 + t;       // A: 128 rows x 8 chunks
      const int r = s >> 3, c = s & 7;
      gload_lds16(Ap + (long)r * K + kt + ((c ^ (r & 7)) * 8), As + s * 8);
    }
#pragma unroll
    for (int i = 0; i < 2; ++i) {
      const int s = i * 256 + t;       // B: 64 rows x 8 chunks
      const int r = s >> 3, c = s & 7;
      gload_lds16(Bp + (long)r * K + kt + ((c ^ (r & 7)) * 8), Bs + s * 8);
    }
    __syncthreads();
#pragma unroll
    for (int ks = 0; ks < 2; ++ks) {
      const int kch = ks * 4 + l4;
      f16x8 af[4], bf[2];
#pragma unroll
      for (int mf = 0; mf < 4; ++mf) {
        const int rr = wr * 64 + mf * 16 + l15;
        af[mf] = *reinterpret_cast<const f16x8*>(As + rr * 64 + ((kch ^ (rr & 7)) * 8));
      }
#pragma unroll
      for (int nf = 0; nf < 2; ++nf) {
        const int rr = wc * 32 + nf * 16 + l15;
        bf[nf] = *reinterpret_cast<const f16x8*>(Bs + rr * 64 + ((kch ^ (rr & 7)) * 8));
      }
#pragma unroll
      for (int mf = 0; mf < 4; ++mf)
#pragma unroll
        for (int nf = 0; nf < 2; ++nf)
          acc[mf][nf] = __builtin_amdgcn_mfma_f32_16x16x32_f16(af[mf], bf[nf], acc[mf][nf], 0, 0, 0);
    }
    __syncthreads();
  }

#pragma unroll
  for (int mf = 0; mf < 4; ++mf)
#pragma unroll
    for (int nf = 0; nf < 2; ++nf) {
      const long col = col0 + wc * 32 + nf * 16 + l15;
#pragma unroll
      for (int r = 0; r < 4; ++r) {
        const long row = row0 + wr * 64 + mf * 16 + l4 * 4 + r;
        Cf32[row * N + col] = acc[mf][nf][r];
      }
    }
}

// ---------------- sparse attention v7: lane-local softmax/PV ------------------
__global__ __launch_bounds__(256) void attn_v7(
    const f16* __restrict__ qm, const f16* __restrict__ Kh,
    const f16* __restrict__ Vh, const int* __restrict__ attn_idx,
    f16* __restrict__ aout) {
  __shared__ f16 qs[32][72];
  __shared__ int ism[32][36];

  const int t = threadIdx.x;
  const int w = t >> 6, lane = t & 63;

  const int bid = blockIdx.x;
  const int combo = 4 * (bid & 7) + ((bid >> 3) & 3);
  const int chunk = bid >> 5;
  const int b = combo >> 4, h = combo & 15;
  const int s0 = chunk * 32;
  const long kvbase = (long)combo * 2048 * 64;

  {
    const int bq = t >> 3, part = t & 7;
    const long row = (long)(b * 2048 + s0 + bq);
    *reinterpret_cast<f16x8*>(&qs[bq][part * 8]) =
        *reinterpret_cast<const f16x8*>(qm + row * 1024 + h * 64 + part * 8);
    const int4 iv = *reinterpret_cast<const int4*>(attn_idx + row * 32 + part * 4);
    *reinterpret_cast<int4*>(&ism[bq][part * 4]) = iv;
  }
  __syncthreads();

  const int qg = lane >> 3, c = lane & 7;
  const int bq = w * 8 + qg;
  const f16x8 qv = *reinterpret_cast<const f16x8*>(&qs[bq][c * 8]);
  const f16* kbase = Kh + kvbase + c * 8;
  const f16* vbase = Vh + kvbase + c * 8;

  float sc[32];
#pragma unroll
  for (int jb = 0; jb < 8; ++jb) {
    const int4 r4 = *reinterpret_cast<const int4*>(&ism[bq][jb * 4]);
    const int rr[4] = {r4.x, r4.y, r4.z, r4.w};
#pragma unroll
    for (int i = 0; i < 4; ++i) {
      const f16x8 kk = *reinterpret_cast<const f16x8*>(kbase + (long)rr[i] * 64);
      float s = dot8(qv, kk, 0.f);
      s += __shfl_xor(s, 1, 64);
      s += __shfl_xor(s, 2, 64);
      s += __shfl_xor(s, 4, 64);
      sc[jb * 4 + i] = s;
    }
  }

  float m = sc[0];
#pragma unroll
  for (int jj = 1; jj < 32; ++jj) m = fmaxf(m, sc[jj]);
  float sum = 0.f;
#pragma unroll
  for (int jj = 0; jj < 32; ++jj) {
    sc[jj] = __expf(sc[jj] - m);
    sum += sc[jj];
  }
  const float inv = __frcp_rn(sum);

  float acc[8] = {};
#pragma unroll
  for (int jb = 0; jb < 8; ++jb) {
    const int4 r4 = *reinterpret_cast<const int4*>(&ism[bq][jb * 4]);
    const int rr[4] = {r4.x, r4.y, r4.z, r4.w};
#pragma unroll
    for (int i = 0; i < 4; ++i) {
      const f16x8 vv = *reinterpret_cast<const f16x8*>(vbase + (long)rr[i] * 64);
      const float p = sc[jb * 4 + i];
#pragma unroll
      for (int e = 0; e < 8; ++e) acc[e] += p * (float)vv[e];
    }
  }
  f16x8 oo;
#pragma unroll
  for (int e = 0; e < 8; ++e) oo[e] = (f16)(acc[e] * inv);
  const long orow = (long)(b * 2048 + s0 + bq);
  *reinterpret_cast<f16x8*>(aout + orow * 1024 + h * 64 + c * 8) = oo;
}

// ---------------- launch ------------------------------------------------------
extern "C" void kernel_launch(void* const* d_in, const int* in_sizes, int n_in,
                              void* d_out, int out_size, void* d_ws, size_t ws_size,
                              hipStream_t stream) {
  const float* x = (const float*)d_in[0];
  const int* aidx = (const int*)d_in[1];
  const float* Wq = (const float*)d_in[3];
  const float* Wk = (const float*)d_in[4];
  const float* Wv = (const float*)d_in[5];
  const float* Wo = (const float*)d_in[6];
  float* out = (float*)d_out;

  f16* xh = (f16*)d_ws;                      // 4096x1024
  f16* wqkv = xh + (long)NM * NDM;           // 3072x1024
  f16* woh = wqkv + (long)3 * NDM * NDM;     // 1024x1024
  f16* qm = woh + (long)NDM * NDM;           // 4096x1024 (q, scaled)
  f16* Khm = qm + (long)NM * NDM;
  f16* Vhm = Khm + (long)NM * NDM;
  f16* aout = Vhm + (long)NM * NDM;

  cvt_all<<<(NM * NDM / 4 + 4 * NDM * NDM / 4) / 256, 256, 0, stream>>>(
      x, Wq, Wk, Wv, Wo, xh);

  dim3 g1(3 * NDM / 128, NM / 128);  // 24 x 32 = 768 blocks, 3/CU
  gemm128_qkv<<<g1, 256, 0, stream>>>(xh, wqkv, qm, Khm, Vhm, NM, 3 * NDM, NDM);

  attn_v7<<<2048, 256, 0, stream>>>(qm, Khm, Vhm, aidx, aout);

  dim3 g2(NDM / 64, NM / 128);  // 16 x 32 = 512 blocks, 2/CU
  gemm128x64_f32<<<g2, 256, 0, stream>>>(aout, woh, out, NM, NDM, NDM);
}